// Round 7
// baseline (1397.205 us; speedup 1.0000x reference)
//
#include <hip/hip_runtime.h>

#define NN 16384   // n_nodes
#define DD 64      // feature dim

typedef _Float16 f16x8 __attribute__((ext_vector_type(8)));
typedef float    f32x4 __attribute__((ext_vector_type(4)));
typedef int      i32x4 __attribute__((ext_vector_type(4)));

// k-permutation within each 32-wide k-step: logical j of lane-group q maps to
// physical k = q*4 + (j&3) + (j>=4 ? 16 : 0). A-load instr pair covers bytes
// [0,64) and [64,128) of each row's kstep window. prep_x writes B in the same
// permuted order -> MFMA dot product unchanged (k-permutation-invariant).
__device__ __forceinline__ int kperm(int q, int j) {
    return q * 4 + (j & 3) + ((j >> 2) << 4);
}

// ---------------------------------------------------------------------------
// Pre-pass: x (fp32 [NN][64]) -> f16 in permuted MFMA B-fragment order:
//   ws[((t*4 + c)*64 + l)*8 + j] = x[32*t + kperm(l>>4, j)][c*16 + (l&15)]
// 2 MiB total -> L2-resident for the whole GEMM.
// ---------------------------------------------------------------------------
__global__ __launch_bounds__(256) void prep_x(const float* __restrict__ x,
                                              _Float16* __restrict__ ws) {
    int tid = blockIdx.x * 256 + threadIdx.x;   // (t*4+c)*64 + l ; 131072 total
    int l  = tid & 63;
    int tc = tid >> 6;
    int c  = tc & 3;
    int t  = tc >> 2;
    int q  = l >> 4;
    int m  = l & 15;
    int col = c * 16 + m;
    f16x8 v;
#pragma unroll
    for (int j = 0; j < 8; ++j) {
        int row = t * 32 + kperm(q, j);
        v[j] = (_Float16)x[(size_t)row * DD + col];
    }
    *(f16x8*)(ws + (size_t)tid * 8) = v;
}

// ---------------------------------------------------------------------------
// Main GEMM: 256-thread blocks, 4 waves. Block owns 16 rows; wave w owns the
// K-range [w*4096, (w+1)*4096) (64 chunks of 64k). 16 waves/CU -> real TLP.
// Low VGPR footprint (chunk=64k) so the A double-buffer stays fully in
// flight. Partial accumulators reduced across waves via LDS at the end.
// ---------------------------------------------------------------------------
__global__ __launch_bounds__(256, 4) void graphpool_gemm(const int* __restrict__ adj,
                                                         const float* __restrict__ x,
                                                         const _Float16* __restrict__ xs,
                                                         float* __restrict__ out) {
    __shared__ float red[4 * 1024];   // 4 waves x 16x64 partial tile

    const int tid = threadIdx.x;
    const int w   = tid >> 6;        // k-split index (wave)
    const int l   = tid & 63;
    const int q   = l >> 4;
    const int m   = l & 15;
    const int row16 = blockIdx.x * 16;

    // A: lane (m,q), chunk n, kstep s: dwordx4 at base+n*64+s*32 (+16 for hi)
    const int* aptr = adj + (size_t)(row16 + m) * NN + w * 4096 + q * 4;
    // B: frag f of wave-local chunk n at bbase + (n*8 + f)*64   (f = s*4+c)
    const f16x8* bbase = (const f16x8*)xs + (size_t)w * 128 * 256 + l;

    f32x4 acc[4];
#pragma unroll
    for (int c = 0; c < 4; ++c) acc[c] = (f32x4){0.f, 0.f, 0.f, 0.f};

    i32x4 areg[2][2][2];   // [buf][kstep s][lo/hi] : 32 VGPRs
    f16x8 breg[8];         // single logical buffer  : 32 VGPRs (+renames)

    auto loadA = [&](int n, int buf) {
        const int* base = aptr + n * 64;
#pragma unroll
        for (int s = 0; s < 2; ++s) {
            areg[buf][s][0] = *(const i32x4*)(base + s * 32);
            areg[buf][s][1] = *(const i32x4*)(base + s * 32 + 16);
        }
    };
    auto loadB = [&](int n) {
        const f16x8* src = bbase + n * 8 * 64;
#pragma unroll
        for (int f = 0; f < 8; ++f) breg[f] = src[f * 64];
    };
    auto compute = [&](int buf) {
#pragma unroll
        for (int s = 0; s < 2; ++s) {
            i32x4 v0 = areg[buf][s][0], v1 = areg[buf][s][1];
            i32x4 p;   // adj in {0,1}: pack two f16 per dword pair
            p.x = (v0.x + (v0.y << 16)) * 0x3C00;
            p.y = (v0.z + (v0.w << 16)) * 0x3C00;
            p.z = (v1.x + (v1.y << 16)) * 0x3C00;
            p.w = (v1.z + (v1.w << 16)) * 0x3C00;
            f16x8 af = __builtin_bit_cast(f16x8, p);
#pragma unroll
            for (int c = 0; c < 4; ++c)
                acc[c] = __builtin_amdgcn_mfma_f32_16x16x32_f16(af, breg[s * 4 + c],
                                                                acc[c], 0, 0, 0);
        }
    };

    loadB(0);
    loadA(0, 0);
    for (int n = 0; n < 64; n += 2) {
        if (n + 1 < 64) loadA(n + 1, 1);
        compute(0);                      // consumes B(n), A(n)
        loadB(n + 1);                    // B for the next compute
        if (n + 2 < 64) loadA(n + 2, 0);
        compute(1);                      // consumes B(n+1), A(n+1)
        if (n + 2 < 64) loadB(n + 2);    // B for next iteration's compute(0)
    }

    // stash partial tile: red[w*1024 + (c*4+i)*64 + l] = acc[c][i]
#pragma unroll
    for (int c = 0; c < 4; ++c)
#pragma unroll
        for (int i = 0; i < 4; ++i)
            red[w * 1024 + (c * 4 + i) * 64 + l] = acc[c][i];
    __syncthreads();

    // reduce 4 partials + self term; thread tid -> col=tid&63, rows rr*4+g
    {
        int col = tid & 63;
        int g   = tid >> 6;          // = reg index i
        int c   = col >> 4;
        int mm  = col & 15;
#pragma unroll
        for (int rr = 0; rr < 4; ++rr) {
            int r = rr * 4 + g;      // q = rr, i = g
            float s = x[(size_t)(row16 + r) * DD + col];
#pragma unroll
            for (int ww = 0; ww < 4; ++ww)
                s += red[ww * 1024 + (c * 4 + g) * 64 + rr * 16 + mm];
            out[(size_t)(row16 + r) * DD + col] = s;
        }
    }
}

// ---------------------------------------------------------------------------
// Safety-net fallback if ws is too small for the swizzled x (2 MiB).
// ---------------------------------------------------------------------------
__global__ void graphpool_fallback(const int* __restrict__ adj,
                                   const float* __restrict__ x,
                                   float* __restrict__ out) {
    int i = blockIdx.x;
    int d = threadIdx.x;   // 64 threads
    float acc = x[(size_t)i * DD + d];
    const int* row = adj + (size_t)i * NN;
    for (int j = 0; j < NN; ++j)
        if (row[j]) acc += x[(size_t)j * DD + d];
    out[(size_t)i * DD + d] = acc;
}

extern "C" void kernel_launch(void* const* d_in, const int* in_sizes, int n_in,
                              void* d_out, int out_size, void* d_ws, size_t ws_size,
                              hipStream_t stream) {
    const float* x   = (const float*)d_in[0];
    const int*   adj = (const int*)d_in[1];
    float*       out = (float*)d_out;

    const size_t ws_needed = (size_t)NN * DD * sizeof(_Float16);   // 2 MiB
    if (ws_size >= ws_needed) {
        _Float16* xs = (_Float16*)d_ws;
        prep_x<<<512, 256, 0, stream>>>(x, xs);
        graphpool_gemm<<<NN / 16, 256, 0, stream>>>(adj, x, xs, out);
    } else {
        graphpool_fallback<<<NN, 64, 0, stream>>>(adj, x, out);
    }
}